// Round 14
// baseline (1800.493 us; speedup 1.0000x reference)
//
#include <hip/hip_runtime.h>
#include <math.h>

#define BB 512
#define LL 128
#define FD 8
#define HD 512
#define EPSV 1e-5f

typedef __attribute__((ext_vector_type(8))) __bf16 bf16x8;
typedef __attribute__((ext_vector_type(4))) float floatx4;
typedef __attribute__((ext_vector_type(8))) unsigned short us8;

__device__ __forceinline__ float silu_f(float x){ return x / (1.0f + expf(-x)); }
__device__ __forceinline__ float softplus_f(float x){ return (x > 20.0f) ? x : log1pf(expf(x)); }

__device__ __forceinline__ unsigned short f2bf(float x){
    union { float f; unsigned u; } v; v.f = x;
    unsigned r = v.u + 0x7fffu + ((v.u >> 16) & 1u);   // RNE
    return (unsigned short)(r >> 16);
}
__device__ __forceinline__ float bf2f(unsigned short h){
    union { unsigned u; float f; } v; v.u = ((unsigned)h) << 16; return v.f;
}
__device__ __forceinline__ void split_bf(float x, unsigned short* hi, unsigned short* lo){
    unsigned short h = f2bf(x);
    *hi = h;
    *lo = f2bf(x - bf2f(h));
}

// ---------------- embed: h = x @ w0 + b0 -> hi/lo bf16 ----------------
__global__ __launch_bounds__(256) void k_embed(const float* __restrict__ x,
    const float* __restrict__ w0, const float* __restrict__ b0,
    unsigned short* __restrict__ hhi, unsigned short* __restrict__ hlo)
{
    int idx = blockIdx.x*256 + threadIdx.x;      // over rows*HD
    int c = idx & (HD-1);
    int row = idx >> 9;
    const float* xr = x + (size_t)row*FD;
    float acc = b0[c];
    #pragma unroll
    for (int f=0; f<FD; ++f) acc = fmaf(xr[f], w0[f*HD + c], acc);
    unsigned short hi, lo; split_bf(acc, &hi, &lo);
    hhi[idx] = hi; hlo[idx] = lo;
}

// ---------------- weight transpose+split for BOTH layers: W[K][N] -> Wt[N][K] bf16 hi/lo ----------------
__global__ __launch_bounds__(256) void k_cvt2(const float* __restrict__ W0,
    const float* __restrict__ W1,
    unsigned short* __restrict__ Th0, unsigned short* __restrict__ Tl0,
    unsigned short* __restrict__ Th1, unsigned short* __restrict__ Tl1,
    int N, int kbits)
{
    int total = N << kbits;
    int idx = blockIdx.x*256 + threadIdx.x;
    const float* W = W0; unsigned short* Th = Th0; unsigned short* Tl = Tl0;
    if (idx >= total) { idx -= total; W = W1; Th = Th1; Tl = Tl1; }
    int K = 1 << kbits;
    int n = idx >> kbits, k = idx & (K-1);
    float v = W[(size_t)k*N + n];
    unsigned short hi, lo; split_bf(v, &hi, &lo);
    Th[idx] = hi; Tl[idx] = lo;
}

// ---------------- U = xp_w @ dt_w (512x512, B-layout [n][c]) + biasU, both layers ----------------
__global__ __launch_bounds__(256) void k_mkU2(
    const float* __restrict__ xw0, const float* __restrict__ dw0,
    const float* __restrict__ xpb0, const float* __restrict__ dtb0,
    const float* __restrict__ xw1, const float* __restrict__ dw1,
    const float* __restrict__ xpb1, const float* __restrict__ dtb1,
    unsigned short* __restrict__ Uhi0, unsigned short* __restrict__ Ulo0,
    unsigned short* __restrict__ Uhi1, unsigned short* __restrict__ Ulo1,
    float* __restrict__ bU0, float* __restrict__ bU1)
{
    int blk = blockIdx.x, tid = threadIdx.x;
    if (blk < 2048) {
        int layer = blk >> 10;
        const float* xw = layer ? xw1 : xw0;
        const float* dw = layer ? dw1 : dw0;
        unsigned short* Uh = layer ? Uhi1 : Uhi0;
        unsigned short* Ul = layer ? Ulo1 : Ulo0;
        int idx = (blk & 1023)*256 + tid;        // n*512 + c, c fastest
        int n = idx >> 9, c = idx & 511;
        float acc = 0.0f;
        #pragma unroll
        for (int j = 0; j < 16; ++j) acc = fmaf(xw[c*16 + j], dw[j*512 + n], acc);
        unsigned short hi, lo; split_bf(acc, &hi, &lo);
        Uh[idx] = hi; Ul[idx] = lo;
    } else {
        int q = blk - 2048;                      // 0..3
        int layer = q >> 1;
        const float* xpb = layer ? xpb1 : xpb0;
        const float* dw  = layer ? dw1  : dw0;
        const float* dtb = layer ? dtb1 : dtb0;
        float* bU = layer ? bU1 : bU0;
        int n = (q & 1)*256 + tid;
        float acc = dtb[n];
        #pragma unroll
        for (int j = 0; j < 16; ++j) acc = fmaf(xpb[j], dw[j*512 + n], acc);
        bU[n] = acc;
    }
}

// ---------------- split-bf16 MFMA GEMM, 128x128 tile, 8 waves (512 thr), 16x16x32, BK=64 ----------------
// (round-13 structure — measured best: BK=64 halves barrier pairs; 64 KB staging LDS is
// free because the kernel is register/bounds-capped at 2 blocks/CU.)
// Grid: blockIdx.x = M-tile (fast, XCD round-robin shares B-strip), blockIdx.y = N-strip.
// MODE 0 (in_proj, K=512, N=1024):
//    nBase<512  (z):  silu -> Abig[row][512+col] bf16 hi/lo
//    nBase>=512 (xi): fused depthwise conv3+silu along rows -> xc[row][col-512] bf16 hi/lo
// MODE 1 (out_proj, K=1024, N=512): outF = v + bias (fp32; residual added in k_ln)
// MODE 2 (dt, K=512, N=512): A=xc; out = xc * softplus(v + biasU) -> Abig[row][col] hi/lo
template<int KDIM, int MODE>
__global__ __launch_bounds__(512, 4) void k_mgemm(
    const unsigned short* __restrict__ Ahi, const unsigned short* __restrict__ Alo,
    const unsigned short* __restrict__ Bhi, const unsigned short* __restrict__ Blo,
    const float* __restrict__ bias,
    const float* __restrict__ cw, const float* __restrict__ cb,
    float* __restrict__ outF,
    unsigned short* __restrict__ oAhi, unsigned short* __restrict__ oAlo,
    unsigned short* __restrict__ xchi, unsigned short* __restrict__ xclo)
{
    __shared__ __align__(16) char smem[65536];   // 4 bufs x 2 subs x 4KB staging; epilogue reuses 33280B
    unsigned short* lds = (unsigned short*)smem;
    const int tid  = threadIdx.x;
    const int wv   = tid >> 6, lane = tid & 63;
    const int quad = lane >> 4, l16 = lane & 15;
    const size_t mBase = (size_t)blockIdx.x * 128;   // M fast — XCD round-robin shares B-strip
    const int nBase = blockIdx.y * 128;
    const int wm = (wv & 3) * 32, wn = (wv >> 2) * 64;

    floatx4 acc[2][4] = {};

    const int rowIn = lane >> 2;                 // 0..15
    const int kofs  = (lane & 3) * 8;            // bf16 units within 32-wide k sub-tile
    const unsigned short* gsrc[4];
    gsrc[0] = Ahi + mBase * KDIM;
    gsrc[1] = Alo + mBase * KDIM;
    gsrc[2] = Bhi + (size_t)nBase * KDIM;
    gsrc[3] = Blo + (size_t)nBase * KDIM;

    for (int k0 = 0; k0 < KDIM; k0 += 64) {
        // stage 4 operand tiles x 2 k-sub-tiles; 8 global_load_lds per thread
        #pragma unroll
        for (int b = 0; b < 4; ++b) {
            #pragma unroll
            for (int s = 0; s < 2; ++s) {
                int row = wv * 16 + rowIn;
                const unsigned short* g = gsrc[b] + (size_t)row * KDIM + k0 + s*32 + kofs;
                unsigned short* l = &lds[b * 8192 + s * 4096 + wv * 512]; // +lane*16B implicit
                __builtin_amdgcn_global_load_lds(
                    (const __attribute__((address_space(1))) void*)g,
                    (__attribute__((address_space(3))) void*)l, 16, 0, 0);
            }
        }
        __syncthreads();
        #pragma unroll
        for (int s = 0; s < 2; ++s) {
            const int kb = s * 4096;
            bf16x8 ah[2], al[2];
            #pragma unroll
            for (int i = 0; i < 2; ++i) {
                int am = wm + 16*i + l16;
                ah[i] = *(const bf16x8*)&lds[0*8192 + kb + am*32 + quad*8];
                al[i] = *(const bf16x8*)&lds[1*8192 + kb + am*32 + quad*8];
            }
            #pragma unroll
            for (int j = 0; j < 4; ++j) {
                int bn = wn + 16*j + l16;
                bf16x8 bh = *(const bf16x8*)&lds[2*8192 + kb + bn*32 + quad*8];
                bf16x8 bl = *(const bf16x8*)&lds[3*8192 + kb + bn*32 + quad*8];
                #pragma unroll
                for (int i = 0; i < 2; ++i) {
                    acc[i][j] = __builtin_amdgcn_mfma_f32_16x16x32_bf16(ah[i], bh, acc[i][j], 0, 0, 0);
                    acc[i][j] = __builtin_amdgcn_mfma_f32_16x16x32_bf16(ah[i], bl, acc[i][j], 0, 0, 0);
                    acc[i][j] = __builtin_amdgcn_mfma_f32_16x16x32_bf16(al[i], bh, acc[i][j], 0, 0, 0);
                }
            }
        }
        __syncthreads();
    }

    // ---- unified coalesced epilogue: two 64-col halves through LDS (stride 65) ----
    float* sc = (float*)smem;
    const int q8 = (tid & 7) * 8;                // col chunk within half
    const int rg = tid >> 3;                     // 0..63 row group
    #pragma unroll
    for (int half = 0; half < 2; ++half) {
        __syncthreads();
        if ((wv >> 2) == half) {                 // 4 waves owning this half stage v+bias
            #pragma unroll
            for (int i = 0; i < 2; ++i)
                #pragma unroll
                for (int r = 0; r < 4; ++r) {
                    int rl = wm + 16*i + quad*4 + r;
                    #pragma unroll
                    for (int j = 0; j < 4; ++j) {
                        int cl = 16*j + l16;
                        sc[rl*65 + cl] = acc[i][j][r] + bias[nBase + half*64 + cl];
                    }
                }
        }
        __syncthreads();
        #pragma unroll
        for (int pss = 0; pss < 2; ++pss) {
            int l = pss*64 + rg;                 // row within 128-row tile
            size_t grow = mBase + l;
            if (MODE == 0) {
                if (nBase < 512) {               // z half: silu -> Abig[:,512+col]
                    int gcol = nBase + half*64 + q8;
                    us8 hh, llv;
                    #pragma unroll
                    for (int k = 0; k < 8; ++k) {
                        float s = silu_f(sc[l*65 + q8 + k]);
                        unsigned short hi, lo; split_bf(s, &hi, &lo);
                        hh[k] = hi; llv[k] = lo;
                    }
                    *(us8*)(oAhi + grow*1024 + 512 + gcol) = hh;
                    *(us8*)(oAlo + grow*1024 + 512 + gcol) = llv;
                } else {                         // xi half: conv3+silu -> xc (M-tile = one batch seq)
                    int gcol = (nBase - 512) + half*64 + q8;
                    us8 hh, llv;
                    #pragma unroll
                    for (int k = 0; k < 8; ++k) {
                        int cc = q8 + k;
                        float xm = (l > 0)   ? sc[(l-1)*65 + cc] : 0.0f;
                        float x0 = sc[l*65 + cc];
                        float xp = (l < 127) ? sc[(l+1)*65 + cc] : 0.0f;
                        int gc = gcol + k;
                        float v = cb[gc];
                        v = fmaf(xm, cw[gc*3+0], v);
                        v = fmaf(x0, cw[gc*3+1], v);
                        v = fmaf(xp, cw[gc*3+2], v);
                        v = silu_f(v);
                        unsigned short hi, lo; split_bf(v, &hi, &lo);
                        hh[k] = hi; llv[k] = lo;
                    }
                    *(us8*)(xchi + grow*512 + gcol) = hh;
                    *(us8*)(xclo + grow*512 + gcol) = llv;
                }
            } else if (MODE == 1) {              // fp32 out, float4 x2
                int gcol = nBase + half*64 + q8;
                float4 o0, o1;
                o0.x = sc[l*65+q8+0]; o0.y = sc[l*65+q8+1]; o0.z = sc[l*65+q8+2]; o0.w = sc[l*65+q8+3];
                o1.x = sc[l*65+q8+4]; o1.y = sc[l*65+q8+5]; o1.z = sc[l*65+q8+6]; o1.w = sc[l*65+q8+7];
                *(float4*)(outF + grow*512 + gcol)     = o0;
                *(float4*)(outF + grow*512 + gcol + 4) = o1;
            } else {                             // MODE 2: xid = xc*softplus(v)
                int gcol = nBase + half*64 + q8;
                us8 xh = *(const us8*)(Ahi + grow*512 + gcol);
                us8 xl = *(const us8*)(Alo + grow*512 + gcol);
                us8 hh, llv;
                #pragma unroll
                for (int k = 0; k < 8; ++k) {
                    float xcv = bf2f(xh[k]) + bf2f(xl[k]);
                    float o = xcv * softplus_f(sc[l*65 + q8 + k]);
                    unsigned short hi, lo; split_bf(o, &hi, &lo);
                    hh[k] = hi; llv[k] = lo;
                }
                *(us8*)(oAhi + grow*1024 + gcol) = hh;
                *(us8*)(oAlo + grow*1024 + gcol) = llv;
            }
        }
    }
}

// ---------------- layernorm of (in + resid); emit hi/lo bf16; optional fused reg-mean ----------------
// When doreg!=0 (layer 2): block-partial sum of LN output over its 4 rows (one batch),
// one atomicAdd per channel per block (G12 pre-reduction: 2.1M atomics/chunk ~4 us).
__global__ __launch_bounds__(256) void k_ln(const float* __restrict__ in,
    const unsigned short* rhi, const unsigned short* rlo,
    const float* __restrict__ g, const float* __restrict__ b,
    unsigned short* ohi, unsigned short* olo,
    float* __restrict__ regb, int doreg)
{
    __shared__ float sacc[4][512];
    int wv = threadIdx.x >> 6, lane = threadIdx.x & 63;
    size_t row = (size_t)blockIdx.x * 4 + wv;
    size_t base = row*512 + lane*8;
    float4 v0 = *(const float4*)(in + base);
    float4 v1 = *(const float4*)(in + base + 4);
    us8 rh = *(const us8*)(rhi + base);
    us8 rl = *(const us8*)(rlo + base);
    float vals[8] = {v0.x,v0.y,v0.z,v0.w,v1.x,v1.y,v1.z,v1.w};
    #pragma unroll
    for (int k = 0; k < 8; ++k) vals[k] += bf2f(rh[k]) + bf2f(rl[k]);
    float s = 0.f, q = 0.f;
    #pragma unroll
    for (int k = 0; k < 8; ++k) { s += vals[k]; q += vals[k]*vals[k]; }
    #pragma unroll
    for (int off = 32; off; off >>= 1) { s += __shfl_xor(s, off); q += __shfl_xor(q, off); }
    float mu = s * (1.0f/512.0f);
    float rs = rsqrtf(q*(1.0f/512.0f) - mu*mu + EPSV);
    const float* gp = g + lane*8;
    const float* bp = b + lane*8;
    float4 g0 = *(const float4*)gp, g1 = *(const float4*)(gp+4);
    float4 b0 = *(const float4*)bp, b1 = *(const float4*)(bp+4);
    float gs[8] = {g0.x,g0.y,g0.z,g0.w,g1.x,g1.y,g1.z,g1.w};
    float bs[8] = {b0.x,b0.y,b0.z,b0.w,b1.x,b1.y,b1.z,b1.w};
    us8 hh, ll;
    float o8[8];
    #pragma unroll
    for (int k = 0; k < 8; ++k) {
        float o = (vals[k] - mu) * rs * gs[k] + bs[k];
        o8[k] = o;
        unsigned short hi, lo; split_bf(o, &hi, &lo);
        hh[k] = hi; ll[k] = lo;
    }
    *(us8*)(ohi + base) = hh;
    *(us8*)(olo + base) = ll;
    if (doreg) {
        #pragma unroll
        for (int k = 0; k < 8; ++k) sacc[wv][lane*8 + k] = o8[k];
        __syncthreads();
        if (threadIdx.x < 64) {
            int ch = threadIdx.x * 8;
            int batch = (int)(blockIdx.x >> 5);      // 32 blocks (128 rows) per batch
            #pragma unroll
            for (int k = 0; k < 8; ++k) {
                float s4 = (sacc[0][ch+k] + sacc[1][ch+k]) + (sacc[2][ch+k] + sacc[3][ch+k]);
                atomicAdd(regb + (size_t)batch*512 + ch + k, s4);
            }
        }
    }
}

// ---------------- head: reg from fused buffer; gate softmax+argmax; expert select ----------------
__global__ __launch_bounds__(512) void k_head(
    const unsigned short* __restrict__ hhi, const unsigned short* __restrict__ hlo,
    const float* __restrict__ regb,
    const float* __restrict__ gumbel, const float* __restrict__ gate_w,
    const float* __restrict__ gate_b, const float* __restrict__ actor_w,
    const float* __restrict__ actor_b, const float* __restrict__ critic_w,
    const float* __restrict__ critic_b, float* __restrict__ out, int bofs)
{
    __shared__ float sred[8][4];
    __shared__ float sg;
    __shared__ int sestar;
    int bl = blockIdx.x, tid = threadIdx.x;      // tid = channel
    int b = bofs + bl;
    size_t base = (size_t)bl * LL * HD;
    float r0 = regb[(size_t)bl*512 + tid] * (1.0f/LL);
    size_t od = base + (LL-1)*HD + tid;
    float dec0 = bf2f(hhi[od]) + bf2f(hlo[od]);

    int lane = tid & 63, wid = tid >> 6;
    float p[4];
    #pragma unroll
    for (int e = 0; e < 4; ++e) p[e] = r0 * gate_w[tid*4 + e];
    #pragma unroll
    for (int e = 0; e < 4; ++e) {
        float v = p[e];
        for (int off = 32; off; off >>= 1) v += __shfl_down(v, off);
        p[e] = v;
    }
    if (!lane) { for (int e = 0; e < 4; ++e) sred[wid][e] = p[e]; }
    __syncthreads();
    if (!tid) {
        float ge[4]; float mx = -1e30f;
        for (int e = 0; e < 4; ++e) {
            float acc = gate_b[e] + gumbel[b*4 + e];
            for (int w = 0; w < 8; ++w) acc += sred[w][e];
            ge[e] = acc;
            if (acc > mx) mx = acc;
        }
        float ys[4], den = 0.f;
        for (int e = 0; e < 4; ++e) { ys[e] = expf(ge[e] - mx); den += ys[e]; }
        int estar = 0; float best = ge[0];
        for (int e = 1; e < 4; ++e) if (ge[e] > best) { best = ge[e]; estar = e; }
        float ye = ys[estar] / den;
        float gv = (1.0f + ye) - ye;             // exactly as reference
        for (int e = 0; e < 4; ++e) out[2048 + b*4 + e] = (e == estar) ? gv : 0.0f;
        sg = gv; sestar = estar;
    }
    __syncthreads();
    float gv = sg; int estar = sestar;
    const float* aw  = actor_w  + (size_t)estar * HD * 3;
    const float* cwp = critic_w + (size_t)estar * HD;
    float q[4];
    #pragma unroll
    for (int a = 0; a < 3; ++a) q[a] = dec0 * aw[tid*3 + a];
    q[3] = dec0 * cwp[tid];
    #pragma unroll
    for (int e = 0; e < 4; ++e) {
        float v = q[e];
        for (int off = 32; off; off >>= 1) v += __shfl_down(v, off);
        q[e] = v;
    }
    __syncthreads();
    if (!lane) { for (int e = 0; e < 4; ++e) sred[wid][e] = q[e]; }
    __syncthreads();
    if (!tid) {
        for (int a = 0; a < 3; ++a) {
            float acc = actor_b[estar*3 + a];
            for (int w = 0; w < 8; ++w) acc += sred[w][a];
            out[b*3 + a] = gv * acc;
        }
        float acc = critic_b[estar];
        for (int w = 0; w < 8; ++w) acc += sred[w][3];
        out[1536 + b] = gv * acc;
    }
}

extern "C" void kernel_launch(void* const* d_in, const int* in_sizes, int n_in,
                              void* d_out, int out_size, void* d_ws, size_t ws_size,
                              hipStream_t stream)
{
    const float* x        = (const float*)d_in[0];
    const float* gumbel   = (const float*)d_in[1];
    const float* w0       = (const float*)d_in[2];
    const float* b0       = (const float*)d_in[3];
    const float* ln_g     = (const float*)d_in[4];
    const float* ln_b     = (const float*)d_in[5];
    const float* gate_w   = (const float*)d_in[6];
    const float* gate_b   = (const float*)d_in[7];
    const float* actor_w  = (const float*)d_in[8];
    const float* actor_b  = (const float*)d_in[9];
    const float* critic_w = (const float*)d_in[10];
    const float* critic_b = (const float*)d_in[11];
    const float* in_w[2]   = {(const float*)d_in[12], (const float*)d_in[22]};
    const float* in_b[2]   = {(const float*)d_in[13], (const float*)d_in[23]};
    const float* conv_w[2] = {(const float*)d_in[14], (const float*)d_in[24]};
    const float* conv_b[2] = {(const float*)d_in[15], (const float*)d_in[25]};
    const float* xp_w[2]   = {(const float*)d_in[16], (const float*)d_in[26]};
    const float* xp_b[2]   = {(const float*)d_in[17], (const float*)d_in[27]};
    const float* dt_w[2]   = {(const float*)d_in[18], (const float*)d_in[28]};
    const float* dt_b[2]   = {(const float*)d_in[19], (const float*)d_in[29]};
    const float* out_w[2]  = {(const float*)d_in[20], (const float*)d_in[30]};
    const float* out_b[2]  = {(const float*)d_in[21], (const float*)d_in[31]};

    // Per-row scratch: union(xb fp32 | xchi+xclo)(2048) + hhi/hlo(2048) + Abig hi/lo(4096)
    // + reg (16 B/row amortized) = 8208 B
    int CB = 512;
    while (CB > 1 && (size_t)CB * LL * 8208 + (17u << 20) > ws_size) CB >>= 1;
    const int rows = CB * LL;
    const size_t CSZ = (size_t)rows * HD;        // elements per 512-wide buffer

    char* p = (char*)d_ws;
    float* xb = (float*)p;                       // union with {xchi, xclo}
    unsigned short* xchi = (unsigned short*)p;
    unsigned short* xclo = xchi + CSZ;           p += CSZ * 4;
    unsigned short* hhi = (unsigned short*)p;    p += CSZ * 2;
    unsigned short* hlo = (unsigned short*)p;    p += CSZ * 2;
    unsigned short* Abig_hi = (unsigned short*)p; p += CSZ * 2 * 2;  // rows x 1024 bf16
    unsigned short* Abig_lo = (unsigned short*)p; p += CSZ * 2 * 2;
    float* regb = (float*)p;                     p += (size_t)CB * 512 * 4;
    unsigned short* wtb = (unsigned short*)p;  p += (size_t)8 * 524288 * 2;
    unsigned short* iwh[2] = {wtb,            wtb + 4*524288};
    unsigned short* iwl[2] = {wtb +   524288, wtb + 5*524288};
    unsigned short* owh[2] = {wtb + 2*524288, wtb + 6*524288};
    unsigned short* owl[2] = {wtb + 3*524288, wtb + 7*524288};
    unsigned short* Uhi[2] = {(unsigned short*)p, (unsigned short*)p + 262144}; p += 262144u * 2 * 2;
    unsigned short* Ulo[2] = {(unsigned short*)p, (unsigned short*)p + 262144}; p += 262144u * 2 * 2;
    float* biasU[2] = {(float*)p, (float*)p + 512};

    // weight transforms: 3 launches
    k_cvt2<<<4096, 256, 0, stream>>>(in_w[0], in_w[1], iwh[0], iwl[0], iwh[1], iwl[1], 1024, 9);
    k_cvt2<<<4096, 256, 0, stream>>>(out_w[0], out_w[1], owh[0], owl[0], owh[1], owl[1], 512, 10);
    k_mkU2<<<2052, 256, 0, stream>>>(xp_w[0], dt_w[0], xp_b[0], dt_b[0],
                                     xp_w[1], dt_w[1], xp_b[1], dt_b[1],
                                     Uhi[0], Ulo[0], Uhi[1], Ulo[1], biasU[0], biasU[1]);

    const int nchunk = BB / CB;
    for (int c = 0; c < nchunk; ++c) {
        const float* xin = x + (size_t)c * CB * LL * FD;
        hipMemsetAsync(regb, 0, (size_t)CB * 512 * sizeof(float), stream);
        k_embed<<<rows*HD/256, 256, 0, stream>>>(xin, w0, b0, hhi, hlo);
        for (int m = 0; m < 2; ++m) {
            // in_proj + fused conv: z->Abig[:,512:], conv(xi)->xc hi/lo   (grid: M fast, N-strip slow)
            k_mgemm<512, 0><<<dim3(rows/128, 8), 512, 0, stream>>>(
                hhi, hlo, iwh[m], iwl[m], in_b[m], conv_w[m], conv_b[m],
                nullptr, Abig_hi, Abig_lo, xchi, xclo);
            // dt GEMM: out = xc * softplus(xc@U + biasU) -> Abig[:,0:512]
            k_mgemm<512, 2><<<dim3(rows/128, 4), 512, 0, stream>>>(
                xchi, xclo, Uhi[m], Ulo[m], biasU[m], nullptr, nullptr,
                nullptr, Abig_hi, Abig_lo, nullptr, nullptr);
            // out_proj: Abig @ out_w + out_b -> xb fp32 (residual added in k_ln)
            k_mgemm<1024, 1><<<dim3(rows/128, 4), 512, 0, stream>>>(
                Abig_hi, Abig_lo, owh[m], owl[m], out_b[m], nullptr, nullptr,
                xb, nullptr, nullptr, nullptr, nullptr);
            // LN(xb + h_resid) -> hhi/hlo; layer 2 also accumulates reg-sum
            k_ln<<<rows/4, 256, 0, stream>>>(xb, hhi, hlo, ln_g, ln_b, hhi, hlo,
                                             regb, (m == 1) ? 1 : 0);
        }
        k_head<<<CB, 512, 0, stream>>>(hhi, hlo, regb, gumbel, gate_w, gate_b,
                                       actor_w, actor_b, critic_w, critic_b,
                                       (float*)d_out, c*CB);
    }
}

// Round 15
// 1701.771 us; speedup vs baseline: 1.0580x; 1.0580x over previous
//
#include <hip/hip_runtime.h>
#include <math.h>

#define BB 512
#define LL 128
#define FD 8
#define HD 512
#define EPSV 1e-5f

typedef __attribute__((ext_vector_type(8))) __bf16 bf16x8;
typedef __attribute__((ext_vector_type(4))) float floatx4;
typedef __attribute__((ext_vector_type(8))) unsigned short us8;

__device__ __forceinline__ float silu_f(float x){ return x / (1.0f + expf(-x)); }
__device__ __forceinline__ float softplus_f(float x){ return (x > 20.0f) ? x : log1pf(expf(x)); }

__device__ __forceinline__ unsigned short f2bf(float x){
    union { float f; unsigned u; } v; v.f = x;
    unsigned r = v.u + 0x7fffu + ((v.u >> 16) & 1u);   // RNE
    return (unsigned short)(r >> 16);
}
__device__ __forceinline__ float bf2f(unsigned short h){
    union { unsigned u; float f; } v; v.u = ((unsigned)h) << 16; return v.f;
}
__device__ __forceinline__ void split_bf(float x, unsigned short* hi, unsigned short* lo){
    unsigned short h = f2bf(x);
    *hi = h;
    *lo = f2bf(x - bf2f(h));
}

// ---------------- embed: h = x @ w0 + b0 -> hi/lo bf16 ----------------
__global__ __launch_bounds__(256) void k_embed(const float* __restrict__ x,
    const float* __restrict__ w0, const float* __restrict__ b0,
    unsigned short* __restrict__ hhi, unsigned short* __restrict__ hlo)
{
    int idx = blockIdx.x*256 + threadIdx.x;      // over rows*HD
    int c = idx & (HD-1);
    int row = idx >> 9;
    const float* xr = x + (size_t)row*FD;
    float acc = b0[c];
    #pragma unroll
    for (int f=0; f<FD; ++f) acc = fmaf(xr[f], w0[f*HD + c], acc);
    unsigned short hi, lo; split_bf(acc, &hi, &lo);
    hhi[idx] = hi; hlo[idx] = lo;
}

// ---------------- weight transpose+split for BOTH layers: W[K][N] -> Wt[N][K] bf16 hi/lo ----------------
__global__ __launch_bounds__(256) void k_cvt2(const float* __restrict__ W0,
    const float* __restrict__ W1,
    unsigned short* __restrict__ Th0, unsigned short* __restrict__ Tl0,
    unsigned short* __restrict__ Th1, unsigned short* __restrict__ Tl1,
    int N, int kbits)
{
    int total = N << kbits;
    int idx = blockIdx.x*256 + threadIdx.x;
    const float* W = W0; unsigned short* Th = Th0; unsigned short* Tl = Tl0;
    if (idx >= total) { idx -= total; W = W1; Th = Th1; Tl = Tl1; }
    int K = 1 << kbits;
    int n = idx >> kbits, k = idx & (K-1);
    float v = W[(size_t)k*N + n];
    unsigned short hi, lo; split_bf(v, &hi, &lo);
    Th[idx] = hi; Tl[idx] = lo;
}

// ---------------- U = xp_w @ dt_w (512x512, B-layout [n][c]) + biasU, both layers ----------------
__global__ __launch_bounds__(256) void k_mkU2(
    const float* __restrict__ xw0, const float* __restrict__ dw0,
    const float* __restrict__ xpb0, const float* __restrict__ dtb0,
    const float* __restrict__ xw1, const float* __restrict__ dw1,
    const float* __restrict__ xpb1, const float* __restrict__ dtb1,
    unsigned short* __restrict__ Uhi0, unsigned short* __restrict__ Ulo0,
    unsigned short* __restrict__ Uhi1, unsigned short* __restrict__ Ulo1,
    float* __restrict__ bU0, float* __restrict__ bU1)
{
    int blk = blockIdx.x, tid = threadIdx.x;
    if (blk < 2048) {
        int layer = blk >> 10;
        const float* xw = layer ? xw1 : xw0;
        const float* dw = layer ? dw1 : dw0;
        unsigned short* Uh = layer ? Uhi1 : Uhi0;
        unsigned short* Ul = layer ? Ulo1 : Ulo0;
        int idx = (blk & 1023)*256 + tid;        // n*512 + c, c fastest
        int n = idx >> 9, c = idx & 511;
        float acc = 0.0f;
        #pragma unroll
        for (int j = 0; j < 16; ++j) acc = fmaf(xw[c*16 + j], dw[j*512 + n], acc);
        unsigned short hi, lo; split_bf(acc, &hi, &lo);
        Uh[idx] = hi; Ul[idx] = lo;
    } else {
        int q = blk - 2048;                      // 0..3
        int layer = q >> 1;
        const float* xpb = layer ? xpb1 : xpb0;
        const float* dw  = layer ? dw1  : dw0;
        const float* dtb = layer ? dtb1 : dtb0;
        float* bU = layer ? bU1 : bU0;
        int n = (q & 1)*256 + tid;
        float acc = dtb[n];
        #pragma unroll
        for (int j = 0; j < 16; ++j) acc = fmaf(xpb[j], dw[j*512 + n], acc);
        bU[n] = acc;
    }
}

// ---------------- split-bf16 MFMA GEMM, 128x128 tile, 8 waves (512 thr), 16x16x32, BK=64 ----------------
// (round-13 structure — measured best: BK=64 halves barrier pairs; 64 KB staging LDS is
// free because the kernel is register/bounds-capped at 2 blocks/CU.)
// Grid: blockIdx.x = M-tile (fast, XCD round-robin shares B-strip), blockIdx.y = N-strip.
// MODE 0 (in_proj, K=512, N=1024):
//    nBase<512  (z):  silu -> Abig[row][512+col] bf16 hi/lo
//    nBase>=512 (xi): fused depthwise conv3+silu along rows -> xc[row][col-512] bf16 hi/lo
// MODE 1 (out_proj, K=1024, N=512): outF = v + bias (fp32; residual added in k_ln)
// MODE 2 (dt, K=512, N=512): A=xc; out = xc * softplus(v + biasU) -> Abig[row][col] hi/lo
template<int KDIM, int MODE>
__global__ __launch_bounds__(512, 4) void k_mgemm(
    const unsigned short* __restrict__ Ahi, const unsigned short* __restrict__ Alo,
    const unsigned short* __restrict__ Bhi, const unsigned short* __restrict__ Blo,
    const float* __restrict__ bias,
    const float* __restrict__ cw, const float* __restrict__ cb,
    float* __restrict__ outF,
    unsigned short* __restrict__ oAhi, unsigned short* __restrict__ oAlo,
    unsigned short* __restrict__ xchi, unsigned short* __restrict__ xclo)
{
    __shared__ __align__(16) char smem[65536];   // 4 bufs x 2 subs x 4KB staging; epilogue reuses 33280B
    unsigned short* lds = (unsigned short*)smem;
    const int tid  = threadIdx.x;
    const int wv   = tid >> 6, lane = tid & 63;
    const int quad = lane >> 4, l16 = lane & 15;
    const size_t mBase = (size_t)blockIdx.x * 128;   // M fast — XCD round-robin shares B-strip
    const int nBase = blockIdx.y * 128;
    const int wm = (wv & 3) * 32, wn = (wv >> 2) * 64;

    floatx4 acc[2][4] = {};

    const int rowIn = lane >> 2;                 // 0..15
    const int kofs  = (lane & 3) * 8;            // bf16 units within 32-wide k sub-tile
    const unsigned short* gsrc[4];
    gsrc[0] = Ahi + mBase * KDIM;
    gsrc[1] = Alo + mBase * KDIM;
    gsrc[2] = Bhi + (size_t)nBase * KDIM;
    gsrc[3] = Blo + (size_t)nBase * KDIM;

    for (int k0 = 0; k0 < KDIM; k0 += 64) {
        // stage 4 operand tiles x 2 k-sub-tiles; 8 global_load_lds per thread
        #pragma unroll
        for (int b = 0; b < 4; ++b) {
            #pragma unroll
            for (int s = 0; s < 2; ++s) {
                int row = wv * 16 + rowIn;
                const unsigned short* g = gsrc[b] + (size_t)row * KDIM + k0 + s*32 + kofs;
                unsigned short* l = &lds[b * 8192 + s * 4096 + wv * 512]; // +lane*16B implicit
                __builtin_amdgcn_global_load_lds(
                    (const __attribute__((address_space(1))) void*)g,
                    (__attribute__((address_space(3))) void*)l, 16, 0, 0);
            }
        }
        __syncthreads();
        #pragma unroll
        for (int s = 0; s < 2; ++s) {
            const int kb = s * 4096;
            bf16x8 ah[2], al[2];
            #pragma unroll
            for (int i = 0; i < 2; ++i) {
                int am = wm + 16*i + l16;
                ah[i] = *(const bf16x8*)&lds[0*8192 + kb + am*32 + quad*8];
                al[i] = *(const bf16x8*)&lds[1*8192 + kb + am*32 + quad*8];
            }
            #pragma unroll
            for (int j = 0; j < 4; ++j) {
                int bn = wn + 16*j + l16;
                bf16x8 bh = *(const bf16x8*)&lds[2*8192 + kb + bn*32 + quad*8];
                bf16x8 bl = *(const bf16x8*)&lds[3*8192 + kb + bn*32 + quad*8];
                #pragma unroll
                for (int i = 0; i < 2; ++i) {
                    acc[i][j] = __builtin_amdgcn_mfma_f32_16x16x32_bf16(ah[i], bh, acc[i][j], 0, 0, 0);
                    acc[i][j] = __builtin_amdgcn_mfma_f32_16x16x32_bf16(ah[i], bl, acc[i][j], 0, 0, 0);
                    acc[i][j] = __builtin_amdgcn_mfma_f32_16x16x32_bf16(al[i], bh, acc[i][j], 0, 0, 0);
                }
            }
        }
        __syncthreads();
    }

    // ---- unified coalesced epilogue: two 64-col halves through LDS (stride 65) ----
    float* sc = (float*)smem;
    const int q8 = (tid & 7) * 8;                // col chunk within half
    const int rg = tid >> 3;                     // 0..63 row group
    #pragma unroll
    for (int half = 0; half < 2; ++half) {
        __syncthreads();
        if ((wv >> 2) == half) {                 // 4 waves owning this half stage v+bias
            #pragma unroll
            for (int i = 0; i < 2; ++i)
                #pragma unroll
                for (int r = 0; r < 4; ++r) {
                    int rl = wm + 16*i + quad*4 + r;
                    #pragma unroll
                    for (int j = 0; j < 4; ++j) {
                        int cl = 16*j + l16;
                        sc[rl*65 + cl] = acc[i][j][r] + bias[nBase + half*64 + cl];
                    }
                }
        }
        __syncthreads();
        #pragma unroll
        for (int pss = 0; pss < 2; ++pss) {
            int l = pss*64 + rg;                 // row within 128-row tile
            size_t grow = mBase + l;
            if (MODE == 0) {
                if (nBase < 512) {               // z half: silu -> Abig[:,512+col]
                    int gcol = nBase + half*64 + q8;
                    us8 hh, llv;
                    #pragma unroll
                    for (int k = 0; k < 8; ++k) {
                        float s = silu_f(sc[l*65 + q8 + k]);
                        unsigned short hi, lo; split_bf(s, &hi, &lo);
                        hh[k] = hi; llv[k] = lo;
                    }
                    *(us8*)(oAhi + grow*1024 + 512 + gcol) = hh;
                    *(us8*)(oAlo + grow*1024 + 512 + gcol) = llv;
                } else {                         // xi half: conv3+silu -> xc (M-tile = one batch seq)
                    int gcol = (nBase - 512) + half*64 + q8;
                    us8 hh, llv;
                    #pragma unroll
                    for (int k = 0; k < 8; ++k) {
                        int cc = q8 + k;
                        float xm = (l > 0)   ? sc[(l-1)*65 + cc] : 0.0f;
                        float x0 = sc[l*65 + cc];
                        float xp = (l < 127) ? sc[(l+1)*65 + cc] : 0.0f;
                        int gc = gcol + k;
                        float v = cb[gc];
                        v = fmaf(xm, cw[gc*3+0], v);
                        v = fmaf(x0, cw[gc*3+1], v);
                        v = fmaf(xp, cw[gc*3+2], v);
                        v = silu_f(v);
                        unsigned short hi, lo; split_bf(v, &hi, &lo);
                        hh[k] = hi; llv[k] = lo;
                    }
                    *(us8*)(xchi + grow*512 + gcol) = hh;
                    *(us8*)(xclo + grow*512 + gcol) = llv;
                }
            } else if (MODE == 1) {              // fp32 out, float4 x2
                int gcol = nBase + half*64 + q8;
                float4 o0, o1;
                o0.x = sc[l*65+q8+0]; o0.y = sc[l*65+q8+1]; o0.z = sc[l*65+q8+2]; o0.w = sc[l*65+q8+3];
                o1.x = sc[l*65+q8+4]; o1.y = sc[l*65+q8+5]; o1.z = sc[l*65+q8+6]; o1.w = sc[l*65+q8+7];
                *(float4*)(outF + grow*512 + gcol)     = o0;
                *(float4*)(outF + grow*512 + gcol + 4) = o1;
            } else {                             // MODE 2: xid = xc*softplus(v)
                int gcol = nBase + half*64 + q8;
                us8 xh = *(const us8*)(Ahi + grow*512 + gcol);
                us8 xl = *(const us8*)(Alo + grow*512 + gcol);
                us8 hh, llv;
                #pragma unroll
                for (int k = 0; k < 8; ++k) {
                    float xcv = bf2f(xh[k]) + bf2f(xl[k]);
                    float o = xcv * softplus_f(sc[l*65 + q8 + k]);
                    unsigned short hi, lo; split_bf(o, &hi, &lo);
                    hh[k] = hi; llv[k] = lo;
                }
                *(us8*)(oAhi + grow*1024 + gcol) = hh;
                *(us8*)(oAlo + grow*1024 + gcol) = llv;
            }
        }
    }
}

// ---------------- layernorm of (in + resid) per row; emit hi/lo bf16 (in-place over resid) ----------------
__global__ __launch_bounds__(256) void k_ln(const float* __restrict__ in,
    const unsigned short* rhi, const unsigned short* rlo,
    const float* __restrict__ g, const float* __restrict__ b,
    unsigned short* ohi, unsigned short* olo)
{
    int wv = threadIdx.x >> 6, lane = threadIdx.x & 63;
    size_t row = (size_t)blockIdx.x * 4 + wv;
    size_t base = row*512 + lane*8;
    float4 v0 = *(const float4*)(in + base);
    float4 v1 = *(const float4*)(in + base + 4);
    us8 rh = *(const us8*)(rhi + base);
    us8 rl = *(const us8*)(rlo + base);
    float vals[8] = {v0.x,v0.y,v0.z,v0.w,v1.x,v1.y,v1.z,v1.w};
    #pragma unroll
    for (int k = 0; k < 8; ++k) vals[k] += bf2f(rh[k]) + bf2f(rl[k]);
    float s = 0.f, q = 0.f;
    #pragma unroll
    for (int k = 0; k < 8; ++k) { s += vals[k]; q += vals[k]*vals[k]; }
    #pragma unroll
    for (int off = 32; off; off >>= 1) { s += __shfl_xor(s, off); q += __shfl_xor(q, off); }
    float mu = s * (1.0f/512.0f);
    float rs = rsqrtf(q*(1.0f/512.0f) - mu*mu + EPSV);
    const float* gp = g + lane*8;
    const float* bp = b + lane*8;
    float4 g0 = *(const float4*)gp, g1 = *(const float4*)(gp+4);
    float4 b0 = *(const float4*)bp, b1 = *(const float4*)(bp+4);
    float gs[8] = {g0.x,g0.y,g0.z,g0.w,g1.x,g1.y,g1.z,g1.w};
    float bs[8] = {b0.x,b0.y,b0.z,b0.w,b1.x,b1.y,b1.z,b1.w};
    us8 hh, ll;
    #pragma unroll
    for (int k = 0; k < 8; ++k) {
        float o = (vals[k] - mu) * rs * gs[k] + bs[k];
        unsigned short hi, lo; split_bf(o, &hi, &lo);
        hh[k] = hi; ll[k] = lo;
    }
    *(us8*)(ohi + base) = hh;
    *(us8*)(olo + base) = ll;
}

// ---------------- k_rsum: partial reg sums — grid (CB, 4), each block sums a 32-row quarter ----------------
// Fixes k_head's 0.5-blocks/CU serial scan (CB=128 -> 512 blocks here, 2/CU).
__global__ __launch_bounds__(256) void k_rsum(
    const unsigned short* __restrict__ hhi, const unsigned short* __restrict__ hlo,
    float* __restrict__ regp)
{
    __shared__ float sacc[4][512];
    int wv = threadIdx.x >> 6, lane = threadIdx.x & 63;
    int bl = blockIdx.x, part = blockIdx.y;      // batch, quarter of sequence
    size_t base = ((size_t)bl * LL + part*32 + wv*8) * HD + lane*8;
    float a[8] = {};
    #pragma unroll
    for (int r = 0; r < 8; ++r) {
        us8 h = *(const us8*)(hhi + base + (size_t)r*HD);
        us8 l = *(const us8*)(hlo + base + (size_t)r*HD);
        #pragma unroll
        for (int k = 0; k < 8; ++k) a[k] += bf2f(h[k]) + bf2f(l[k]);
    }
    #pragma unroll
    for (int k = 0; k < 8; ++k) sacc[wv][lane*8 + k] = a[k];
    __syncthreads();
    int ch = threadIdx.x * 2;
    float s0 = (sacc[0][ch]   + sacc[1][ch])   + (sacc[2][ch]   + sacc[3][ch]);
    float s1 = (sacc[0][ch+1] + sacc[1][ch+1]) + (sacc[2][ch+1] + sacc[3][ch+1]);
    float2 o; o.x = s0; o.y = s1;
    *(float2*)(regp + ((size_t)bl*4 + part)*512 + ch) = o;
}

// ---------------- head: reg from partials; gate softmax+argmax; expert select ----------------
__global__ __launch_bounds__(512) void k_head(
    const unsigned short* __restrict__ hhi, const unsigned short* __restrict__ hlo,
    const float* __restrict__ regp,
    const float* __restrict__ gumbel, const float* __restrict__ gate_w,
    const float* __restrict__ gate_b, const float* __restrict__ actor_w,
    const float* __restrict__ actor_b, const float* __restrict__ critic_w,
    const float* __restrict__ critic_b, float* __restrict__ out, int bofs)
{
    __shared__ float sred[8][4];
    __shared__ float sg;
    __shared__ int sestar;
    int bl = blockIdx.x, tid = threadIdx.x;      // tid = channel
    int b = bofs + bl;
    size_t base = (size_t)bl * LL * HD;
    const float* rp = regp + (size_t)bl*4*512;
    float r0 = ((rp[tid] + rp[512+tid]) + (rp[1024+tid] + rp[1536+tid])) * (1.0f/LL);
    size_t od = base + (LL-1)*HD + tid;
    float dec0 = bf2f(hhi[od]) + bf2f(hlo[od]);

    int lane = tid & 63, wid = tid >> 6;
    float p[4];
    #pragma unroll
    for (int e = 0; e < 4; ++e) p[e] = r0 * gate_w[tid*4 + e];
    #pragma unroll
    for (int e = 0; e < 4; ++e) {
        float v = p[e];
        for (int off = 32; off; off >>= 1) v += __shfl_down(v, off);
        p[e] = v;
    }
    if (!lane) { for (int e = 0; e < 4; ++e) sred[wid][e] = p[e]; }
    __syncthreads();
    if (!tid) {
        float ge[4]; float mx = -1e30f;
        for (int e = 0; e < 4; ++e) {
            float acc = gate_b[e] + gumbel[b*4 + e];
            for (int w = 0; w < 8; ++w) acc += sred[w][e];
            ge[e] = acc;
            if (acc > mx) mx = acc;
        }
        float ys[4], den = 0.f;
        for (int e = 0; e < 4; ++e) { ys[e] = expf(ge[e] - mx); den += ys[e]; }
        int estar = 0; float best = ge[0];
        for (int e = 1; e < 4; ++e) if (ge[e] > best) { best = ge[e]; estar = e; }
        float ye = ys[estar] / den;
        float gv = (1.0f + ye) - ye;             // exactly as reference
        for (int e = 0; e < 4; ++e) out[2048 + b*4 + e] = (e == estar) ? gv : 0.0f;
        sg = gv; sestar = estar;
    }
    __syncthreads();
    float gv = sg; int estar = sestar;
    const float* aw  = actor_w  + (size_t)estar * HD * 3;
    const float* cwp = critic_w + (size_t)estar * HD;
    float q[4];
    #pragma unroll
    for (int a = 0; a < 3; ++a) q[a] = dec0 * aw[tid*3 + a];
    q[3] = dec0 * cwp[tid];
    #pragma unroll
    for (int e = 0; e < 4; ++e) {
        float v = q[e];
        for (int off = 32; off; off >>= 1) v += __shfl_down(v, off);
        q[e] = v;
    }
    __syncthreads();
    if (!lane) { for (int e = 0; e < 4; ++e) sred[wid][e] = q[e]; }
    __syncthreads();
    if (!tid) {
        for (int a = 0; a < 3; ++a) {
            float acc = actor_b[estar*3 + a];
            for (int w = 0; w < 8; ++w) acc += sred[w][a];
            out[b*3 + a] = gv * acc;
        }
        float acc = critic_b[estar];
        for (int w = 0; w < 8; ++w) acc += sred[w][3];
        out[1536 + b] = gv * acc;
    }
}

extern "C" void kernel_launch(void* const* d_in, const int* in_sizes, int n_in,
                              void* d_out, int out_size, void* d_ws, size_t ws_size,
                              hipStream_t stream)
{
    const float* x        = (const float*)d_in[0];
    const float* gumbel   = (const float*)d_in[1];
    const float* w0       = (const float*)d_in[2];
    const float* b0       = (const float*)d_in[3];
    const float* ln_g     = (const float*)d_in[4];
    const float* ln_b     = (const float*)d_in[5];
    const float* gate_w   = (const float*)d_in[6];
    const float* gate_b   = (const float*)d_in[7];
    const float* actor_w  = (const float*)d_in[8];
    const float* actor_b  = (const float*)d_in[9];
    const float* critic_w = (const float*)d_in[10];
    const float* critic_b = (const float*)d_in[11];
    const float* in_w[2]   = {(const float*)d_in[12], (const float*)d_in[22]};
    const float* in_b[2]   = {(const float*)d_in[13], (const float*)d_in[23]};
    const float* conv_w[2] = {(const float*)d_in[14], (const float*)d_in[24]};
    const float* conv_b[2] = {(const float*)d_in[15], (const float*)d_in[25]};
    const float* xp_w[2]   = {(const float*)d_in[16], (const float*)d_in[26]};
    const float* xp_b[2]   = {(const float*)d_in[17], (const float*)d_in[27]};
    const float* dt_w[2]   = {(const float*)d_in[18], (const float*)d_in[28]};
    const float* dt_b[2]   = {(const float*)d_in[19], (const float*)d_in[29]};
    const float* out_w[2]  = {(const float*)d_in[20], (const float*)d_in[30]};
    const float* out_b[2]  = {(const float*)d_in[21], (const float*)d_in[31]};

    // Per-row scratch: union(xb fp32 | xchi+xclo)(2048) + hhi/hlo(2048) + Abig hi/lo(4096) = 8192 B
    // Tail: 8.4MB weights + 2MB U + regp (CB*4*512*4 = 1MB at CB=128) < 16MB guard
    int CB = 512;
    while (CB > 1 && (size_t)CB * LL * 8192 + (16u << 20) > ws_size) CB >>= 1;
    const int rows = CB * LL;
    const size_t CSZ = (size_t)rows * HD;        // elements per 512-wide buffer

    char* p = (char*)d_ws;
    float* xb = (float*)p;                       // union with {xchi, xclo}
    unsigned short* xchi = (unsigned short*)p;
    unsigned short* xclo = xchi + CSZ;           p += CSZ * 4;
    unsigned short* hhi = (unsigned short*)p;    p += CSZ * 2;
    unsigned short* hlo = (unsigned short*)p;    p += CSZ * 2;
    unsigned short* Abig_hi = (unsigned short*)p; p += CSZ * 2 * 2;  // rows x 1024 bf16
    unsigned short* Abig_lo = (unsigned short*)p; p += CSZ * 2 * 2;
    unsigned short* wtb = (unsigned short*)p;  p += (size_t)8 * 524288 * 2;
    unsigned short* iwh[2] = {wtb,            wtb + 4*524288};
    unsigned short* iwl[2] = {wtb +   524288, wtb + 5*524288};
    unsigned short* owh[2] = {wtb + 2*524288, wtb + 6*524288};
    unsigned short* owl[2] = {wtb + 3*524288, wtb + 7*524288};
    unsigned short* Uhi[2] = {(unsigned short*)p, (unsigned short*)p + 262144}; p += 262144u * 2 * 2;
    unsigned short* Ulo[2] = {(unsigned short*)p, (unsigned short*)p + 262144}; p += 262144u * 2 * 2;
    float* biasU[2] = {(float*)p, (float*)p + 512};           p += 1024 * 4;
    float* regp = (float*)p;                     // CB x 4 x 512 partial reg sums

    // weight transforms: 3 launches
    k_cvt2<<<4096, 256, 0, stream>>>(in_w[0], in_w[1], iwh[0], iwl[0], iwh[1], iwl[1], 1024, 9);
    k_cvt2<<<4096, 256, 0, stream>>>(out_w[0], out_w[1], owh[0], owl[0], owh[1], owl[1], 512, 10);
    k_mkU2<<<2052, 256, 0, stream>>>(xp_w[0], dt_w[0], xp_b[0], dt_b[0],
                                     xp_w[1], dt_w[1], xp_b[1], dt_b[1],
                                     Uhi[0], Ulo[0], Uhi[1], Ulo[1], biasU[0], biasU[1]);

    const int nchunk = BB / CB;
    for (int c = 0; c < nchunk; ++c) {
        const float* xin = x + (size_t)c * CB * LL * FD;
        k_embed<<<rows*HD/256, 256, 0, stream>>>(xin, w0, b0, hhi, hlo);
        for (int m = 0; m < 2; ++m) {
            // in_proj + fused conv: z->Abig[:,512:], conv(xi)->xc hi/lo   (grid: M fast, N-strip slow)
            k_mgemm<512, 0><<<dim3(rows/128, 8), 512, 0, stream>>>(
                hhi, hlo, iwh[m], iwl[m], in_b[m], conv_w[m], conv_b[m],
                nullptr, Abig_hi, Abig_lo, xchi, xclo);
            // dt GEMM: out = xc * softplus(xc@U + biasU) -> Abig[:,0:512]
            k_mgemm<512, 2><<<dim3(rows/128, 4), 512, 0, stream>>>(
                xchi, xclo, Uhi[m], Ulo[m], biasU[m], nullptr, nullptr,
                nullptr, Abig_hi, Abig_lo, nullptr, nullptr);
            // out_proj: Abig @ out_w + out_b -> xb fp32 (residual added in k_ln)
            k_mgemm<1024, 1><<<dim3(rows/128, 4), 512, 0, stream>>>(
                Abig_hi, Abig_lo, owh[m], owl[m], out_b[m], nullptr, nullptr,
                xb, nullptr, nullptr, nullptr, nullptr);
            // LN(xb + h_resid) -> hhi/hlo (in-place over resid)
            k_ln<<<rows/4, 256, 0, stream>>>(xb, hhi, hlo, ln_g, ln_b, hhi, hlo);
        }
        // wide partial reg-sum (512 blocks), then slim head
        k_rsum<<<dim3(CB, 4), 256, 0, stream>>>(hhi, hlo, regp);
        k_head<<<CB, 512, 0, stream>>>(hhi, hlo, regp, gumbel, gate_w, gate_b,
                                       actor_w, actor_b, critic_w, critic_b,
                                       (float*)d_out, c*CB);
    }
}